// Round 2
// baseline (20715.038 us; speedup 1.0000x reference)
//
#include <hip/hip_runtime.h>
#include <stdint.h>

// LSTM: B=64 S=512 IN=HID=1024, fp32 in/out.
// d_in: x(64,512,1024) U(1024,4096) V(1024,4096) B(4096) h0(64,1024) c0(64,1024)
// d_out: out(64,512,1024) ++ h_fin(64,1024) ++ c_fin(64,1024)
//
// Plan: G = x@U precomputed as one big bf16 MFMA GEMM (no recurrence).
// Persistent 256-block kernel runs the 512-step recurrence: V-slice stationary
// in registers as MFMA B-fragments, h broadcast via bf16 buffer in ws, 4
// independent per-batch-group flag barriers (agent-scope atomics).
//
// R1 fix: gemm_xu LDS staging second-row offset was la0+4096 (OOB, corrupted
// Bs -> NaN G). Correct delta is +512 shorts: (kc*128 + (row^kc*4))*8 with
// row' = row+64 -> index +64 -> *8 shorts = +512.

#define OUT_HF  33554432
#define OUT_CF  33619968

typedef __attribute__((ext_vector_type(8))) short bf16x8;
typedef __attribute__((ext_vector_type(4))) float f32x4;
typedef __attribute__((ext_vector_type(4))) unsigned short u16x4;

// ---- ws layout (bytes) ----
#define WS_G    0                 // bf16 G[32768][4096]    268435456
#define WS_XB   268435456         // bf16 x  [32768][1024]   67108864
#define WS_UT   335544320         // bf16 U^T[4096][1024]     8388608
#define WS_HB   343932928         // bf16 hbuf[2][64][1024]    262144
#define WS_FL   344195072         // int  flags[256*16]         16384

__device__ __forceinline__ unsigned short f2bf(float f) {
  unsigned u = __float_as_uint(f);
  u += 0x7FFFu + ((u >> 16) & 1u);          // RNE
  return (unsigned short)(u >> 16);
}
__device__ __forceinline__ float bf2f(unsigned short b) {
  return __uint_as_float(((unsigned)b) << 16);
}
__device__ __forceinline__ float sigf(float x)   { return 1.0f / (1.0f + __expf(-x)); }
__device__ __forceinline__ float tanhf_(float x) { return 2.0f / (1.0f + __expf(-2.0f * x)) - 1.0f; }

// ---------------- x fp32 -> bf16 ----------------
__global__ void convert_x(const float* __restrict__ x, unsigned short* __restrict__ xb) {
  const int i = (blockIdx.x * 256 + threadIdx.x) * 4;   // grid 32768
  f32x4 v = *(const f32x4*)(x + i);
  u16x4 o;
  o[0] = f2bf(v[0]); o[1] = f2bf(v[1]); o[2] = f2bf(v[2]); o[3] = f2bf(v[3]);
  *(u16x4*)(xb + i) = o;
}

// ---------------- U fp32 (1024x4096) -> bf16 U^T (4096x1024) ----------------
__global__ void transpose_u(const float* __restrict__ U, unsigned short* __restrict__ ut) {
  __shared__ unsigned short t[64 * 65];
  const int kt = blockIdx.x;      // 16
  const int nt = blockIdx.y;      // 64
  const int tid = threadIdx.x;
  const int nn = tid & 63, kq = tid >> 6;
  #pragma unroll
  for (int i = 0; i < 16; ++i) {
    const int kk = kq * 16 + i;
    t[kk * 65 + nn] = f2bf(U[(size_t)(kt * 64 + kk) * 4096 + nt * 64 + nn]);
  }
  __syncthreads();
  const int kk2 = tid & 63, nq = tid >> 6;
  #pragma unroll
  for (int i = 0; i < 16; ++i) {
    const int nn2 = nq * 16 + i;
    ut[(size_t)(nt * 64 + nn2) * 1024 + kt * 64 + kk2] = t[kk2 * 65 + nn2];
  }
}

// ---------------- init: h0 -> bf16 hbuf[0], zero flags ----------------
__global__ void init_misc(const float* __restrict__ h0, unsigned short* __restrict__ hb,
                          int* __restrict__ flags) {
  const int i = blockIdx.x * 256 + threadIdx.x;   // grid 256 -> 65536
  hb[i] = f2bf(h0[i]);
  if (i < 4096) flags[i] = 0;
}

// ---------------- G = x @ U  (bf16 MFMA, 128x128x32 tiles) ----------------
__global__ void __launch_bounds__(256) gemm_xu(const unsigned short* __restrict__ A,
                                               const unsigned short* __restrict__ Bt,
                                               unsigned short* __restrict__ Gb) {
  __shared__ __align__(16) short As[4096];   // swizzled k-chunk-major 128x32
  __shared__ __align__(16) short Bs[4096];
  const int tid = threadIdx.x;
  const int l = tid & 63, w = tid >> 6;
  const int wm = w & 1, wn = w >> 1;
  const int lm = l & 15, lq = l >> 4;
  const int bid = blockIdx.x;
  const int bm = bid & 255, bn = bid >> 8;   // grid 8192 = 256 x 32

  const int i0 = tid >> 2, kc0 = tid & 3;    // staging chunk (row, kchunk)
  const int la0 = (kc0 * 128 + (i0 ^ (kc0 << 2))) * 8;
  const int la1 = la0 + 512;                 // row+64 -> swizzled index +64 -> +512 shorts
  const unsigned short* Ap = A  + (size_t)(bm * 128 + i0) * 1024 + kc0 * 8;
  const unsigned short* Bp = Bt + (size_t)(bn * 128 + i0) * 1024 + kc0 * 8;

  f32x4 acc[4][4] = {};

  for (int kt = 0; kt < 32; ++kt) {
    const int k0 = kt * 32;
    bf16x8 av0 = *(const bf16x8*)(Ap + k0);
    bf16x8 av1 = *(const bf16x8*)(Ap + 64 * 1024 + k0);
    bf16x8 bv0 = *(const bf16x8*)(Bp + k0);
    bf16x8 bv1 = *(const bf16x8*)(Bp + 64 * 1024 + k0);
    __syncthreads();
    *(bf16x8*)(As + la0) = av0;
    *(bf16x8*)(As + la1) = av1;
    *(bf16x8*)(Bs + la0) = bv0;
    *(bf16x8*)(Bs + la1) = bv1;
    __syncthreads();

    bf16x8 af[4], bfv[4];
    #pragma unroll
    for (int mt = 0; mt < 4; ++mt) {
      const int i = wm * 64 + mt * 16 + lm;
      af[mt] = *(const bf16x8*)(As + (lq * 128 + (i ^ (lq << 2))) * 8);
    }
    #pragma unroll
    for (int nt = 0; nt < 4; ++nt) {
      const int i = wn * 64 + nt * 16 + lm;
      bfv[nt] = *(const bf16x8*)(Bs + (lq * 128 + (i ^ (lq << 2))) * 8);
    }
    #pragma unroll
    for (int mt = 0; mt < 4; ++mt)
      #pragma unroll
      for (int nt = 0; nt < 4; ++nt)
        acc[mt][nt] = __builtin_amdgcn_mfma_f32_16x16x32_bf16(af[mt], bfv[nt], acc[mt][nt], 0, 0, 0);
  }

  #pragma unroll
  for (int mt = 0; mt < 4; ++mt)
    #pragma unroll
    for (int nt = 0; nt < 4; ++nt) {
      const int col = bn * 128 + wn * 64 + nt * 16 + lm;
      const int r0  = bm * 128 + wm * 64 + mt * 16 + lq * 4;
      #pragma unroll
      for (int r = 0; r < 4; ++r)
        Gb[(size_t)(r0 + r) * 4096 + col] = f2bf(acc[mt][nt][r]);
    }
}

// ---------------- persistent recurrence ----------------
__global__ void __launch_bounds__(256, 1) lstm_rec(
    const unsigned short* __restrict__ Gb,   // bf16 [32768][4096], row = b*512+t
    const float* __restrict__ V,             // fp32 [1024][4096]
    const float* __restrict__ Bias,          // fp32 [4096]
    const float* __restrict__ c0,            // fp32 [64][1024]
    unsigned short* __restrict__ hb,         // bf16 2x[64][1024]
    int* __restrict__ flags,                 // 256 flags, 64B apart
    float* __restrict__ out) {
  __shared__ __align__(16) float gbuf[4096];  // [w][b16][j16][g4]
  const int tid = threadIdx.x;
  const int l = tid & 63, w = tid >> 6;       // wave w owns k-quarter w
  const int lm = l & 15, lq = l >> 4;
  const int bid = blockIdx.x;
  const int mb = bid & 3;                     // batch group (independent recurrences)
  const int nh = bid >> 2;                    // hidden tile
  const int jh = nh << 4;

  // stationary V fragments: vf[ks][gate], k = w*256 + ks*32 + lq*8 + j, n = jh+lm
  bf16x8 vf[8][4];
  {
    const int col0 = jh + lm;
    #pragma unroll
    for (int ks = 0; ks < 8; ++ks) {
      const int kb = (w << 8) + (ks << 5) + (lq << 3);
      #pragma unroll
      for (int g = 0; g < 4; ++g) {
        const size_t base = (size_t)kb * 4096 + (g << 10) + col0;
        bf16x8 v;
        #pragma unroll
        for (int jj = 0; jj < 8; ++jj)
          v[jj] = (short)f2bf(V[base + (size_t)jj * 4096]);
        vf[ks][g] = v;
      }
    }
  }

  // elementwise state: one cell (b, j) per thread, c stays in a register
  const int b  = tid >> 4;
  const int j  = tid & 15;
  const int gr = (mb << 4) + b;
  float bias_r[4];
  #pragma unroll
  for (int g = 0; g < 4; ++g) bias_r[g] = Bias[(g << 10) + jh + j];
  float c = c0[(gr << 10) + jh + j];

  const int abase  = ((mb << 4) + lm) * 1024 + (w << 8) + (lq << 3);
  const int fidx   = ((l << 2) + mb) << 4;   // lane polls group member l's flag
  const int myflag = bid << 4;

  float gp[4], gn[4];
  {
    const size_t grow = (size_t)(gr << 9) * 4096;
    #pragma unroll
    for (int g = 0; g < 4; ++g) gp[g] = bf2f(Gb[grow + (g << 10) + jh + j]);
  }

  int budget = 5000000;  // hang-safety: bounded spin across the whole kernel

  for (int t = 0; t < 512; ++t) {
    if (t > 0) {
      while (__hip_atomic_load(flags + fidx, __ATOMIC_RELAXED, __HIP_MEMORY_SCOPE_AGENT) < t) {
        if (--budget < 0) break;
        __builtin_amdgcn_s_sleep(1);
      }
      __threadfence();   // acquire: make group's h stores visible
    }

    // A fragments: h tile rows mb*16..+16, this wave's k-quarter (coalesced 64B lines)
    const unsigned short* hp = hb + ((t & 1) << 16);
    bf16x8 a[8];
    #pragma unroll
    for (int ks = 0; ks < 8; ++ks)
      a[ks] = *(const bf16x8*)(hp + abase + (ks << 5));

    // prefetch next step's G slice (no recurrence dependency)
    {
      const int t2 = t < 511 ? t + 1 : t;
      const size_t grow = ((size_t)(gr << 9) + t2) * 4096;
      #pragma unroll
      for (int g = 0; g < 4; ++g) gn[g] = bf2f(Gb[grow + (g << 10) + jh + j]);
    }

    f32x4 acc[4] = {};
    #pragma unroll
    for (int ks = 0; ks < 8; ++ks)
      #pragma unroll
      for (int g = 0; g < 4; ++g)
        acc[g] = __builtin_amdgcn_mfma_f32_16x16x32_bf16(a[ks], vf[ks][g], acc[g], 0, 0, 0);

    // partial (per-wave k-quarter) -> LDS for cross-wave reduction
    #pragma unroll
    for (int g = 0; g < 4; ++g)
      #pragma unroll
      for (int r = 0; r < 4; ++r)
        gbuf[((w << 8) + ((lq << 2) + r) * 16 + lm) * 4 + g] = acc[g][r];

    __syncthreads();

    f32x4 hv = *(const f32x4*)(gbuf + (tid << 2));
    hv += *(const f32x4*)(gbuf + ((256 + tid) << 2));
    hv += *(const f32x4*)(gbuf + ((512 + tid) << 2));
    hv += *(const f32x4*)(gbuf + ((768 + tid) << 2));

    const float pn = hv[0] + gp[0] + bias_r[0];
    const float pi = hv[1] + gp[1] + bias_r[1];
    const float pf = hv[2] + gp[2] + bias_r[2];
    const float po = hv[3] + gp[3] + bias_r[3];
    const float nn = tanhf_(pn);
    const float ii = sigf(pi);
    const float ff = sigf(pf);
    const float oo = sigf(po);
    c = c * ff + nn * ii;
    const float h = tanhf_(c) * oo;

    out[(size_t)gr * 524288 + ((size_t)t << 10) + jh + j] = h;
    hb[((1 - (t & 1)) << 16) + (gr << 10) + jh + j] = f2bf(h);
    if (t == 511) {
      out[OUT_HF + (gr << 10) + jh + j] = h;
      out[OUT_CF + (gr << 10) + jh + j] = c;
    }
    #pragma unroll
    for (int g = 0; g < 4; ++g) gp[g] = gn[g];

    __threadfence();        // publish h stores (agent scope)
    __syncthreads();        // all threads' stores precede the flag release
    if (tid == 0)
      __hip_atomic_store(flags + myflag, t + 1, __ATOMIC_RELEASE, __HIP_MEMORY_SCOPE_AGENT);
  }
}

extern "C" void kernel_launch(void* const* d_in, const int* in_sizes, int n_in,
                              void* d_out, int out_size, void* d_ws, size_t ws_size,
                              hipStream_t stream) {
  const float* x  = (const float*)d_in[0];
  const float* U  = (const float*)d_in[1];
  const float* V  = (const float*)d_in[2];
  const float* Bi = (const float*)d_in[3];
  const float* h0 = (const float*)d_in[4];
  const float* c0 = (const float*)d_in[5];
  float* out = (float*)d_out;
  char* ws = (char*)d_ws;

  unsigned short* Gb = (unsigned short*)(ws + WS_G);
  unsigned short* xb = (unsigned short*)(ws + WS_XB);
  unsigned short* ut = (unsigned short*)(ws + WS_UT);
  unsigned short* hb = (unsigned short*)(ws + WS_HB);
  int* flags         = (int*)(ws + WS_FL);

  convert_x  <<<32768, 256, 0, stream>>>(x, xb);
  transpose_u<<<dim3(16, 64), 256, 0, stream>>>(U, ut);
  init_misc  <<<256, 256, 0, stream>>>(h0, hb, flags);
  gemm_xu    <<<8192, 256, 0, stream>>>(xb, ut, Gb);
  lstm_rec   <<<256, 256, 0, stream>>>(Gb, V, Bi, c0, hb, flags, out);
}

// Round 4
// 2999.794 us; speedup vs baseline: 6.9055x; 6.9055x over previous
//
#include <hip/hip_runtime.h>
#include <stdint.h>

// LSTM: B=64 S=512 IN=HID=1024, fp32 in/out.
// d_in: x(64,512,1024) U(1024,4096) V(1024,4096) B(4096) h0(64,1024) c0(64,1024)
// d_out: out(64,512,1024) ++ h_fin(64,1024) ++ c_fin(64,1024)
//
// G = x@U precomputed as one big bf16 MFMA GEMM. Persistent 256-block kernel
// runs the 512-step recurrence with V stationary in VGPRs as MFMA B-frags.
//
// R3 post-mortem: flag-release (vmcnt(0) then flag store) raced — flag became
// visible at MALL before the write-through h data; replays diverged. R4:
// TAG-IN-DATA. h is exchanged as u32 = bf16(h)<<16 | step_tag; readers spin
// re-loading (sc0 sc1, cache-bypass) until every word's tag == expected step.
// Dword atomicity makes tag/payload inseparable; double-buffer + the natural
// all-to-all dependency make overwrite-before-read impossible. No flags, no
// fences, no store drains.

#define OUT_HF  33554432
#define OUT_CF  33619968

typedef __attribute__((ext_vector_type(8))) short bf16x8;
typedef __attribute__((ext_vector_type(4))) float f32x4;
typedef __attribute__((ext_vector_type(4))) unsigned short u16x4;
typedef __attribute__((ext_vector_type(4))) unsigned int u32x4;

// ---- ws layout (bytes) ----
#define WS_G    0                 // bf16 G[32768][4096]    268435456
#define WS_XB   268435456         // bf16 x  [32768][1024]   67108864 (dead after gemm)
#define WS_HB   268435456         // u32 hbuf[2][64][1024]     524288 (aliases XB; init_h runs after gemm)
#define WS_UT   335544320         // bf16 U^T[4096][1024]     8388608

__device__ __forceinline__ unsigned short f2bf(float f) {
  unsigned u = __float_as_uint(f);
  u += 0x7FFFu + ((u >> 16) & 1u);          // RNE
  return (unsigned short)(u >> 16);
}
__device__ __forceinline__ float bf2f(unsigned short b) {
  return __uint_as_float(((unsigned)b) << 16);
}
__device__ __forceinline__ float sigf(float x)   { return 1.0f / (1.0f + __expf(-x)); }
__device__ __forceinline__ float tanhf_(float x) { return 2.0f / (1.0f + __expf(-2.0f * x)) - 1.0f; }

// ---------------- x fp32 -> bf16 ----------------
__global__ void convert_x(const float* __restrict__ x, unsigned short* __restrict__ xb) {
  const int i = (blockIdx.x * 256 + threadIdx.x) * 4;   // grid 32768
  f32x4 v = *(const f32x4*)(x + i);
  u16x4 o;
  o[0] = f2bf(v[0]); o[1] = f2bf(v[1]); o[2] = f2bf(v[2]); o[3] = f2bf(v[3]);
  *(u16x4*)(xb + i) = o;
}

// ---------------- U fp32 (1024x4096) -> bf16 U^T (4096x1024) ----------------
__global__ void transpose_u(const float* __restrict__ U, unsigned short* __restrict__ ut) {
  __shared__ unsigned short t[64 * 65];
  const int kt = blockIdx.x;      // 16
  const int nt = blockIdx.y;      // 64
  const int tid = threadIdx.x;
  const int nn = tid & 63, kq = tid >> 6;
  #pragma unroll
  for (int i = 0; i < 16; ++i) {
    const int kk = kq * 16 + i;
    t[kk * 65 + nn] = f2bf(U[(size_t)(kt * 64 + kk) * 4096 + nt * 64 + nn]);
  }
  __syncthreads();
  const int kk2 = tid & 63, nq = tid >> 6;
  #pragma unroll
  for (int i = 0; i < 16; ++i) {
    const int nn2 = nq * 16 + i;
    ut[(size_t)(nt * 64 + nn2) * 1024 + kt * 64 + kk2] = t[kk2 * 65 + nn2];
  }
}

// ---------------- init: h0 -> tagged u32 buffer (coherence-point stores) ----
__global__ void init_h(const float* __restrict__ h0, uint32_t* __restrict__ hb32) {
  const int i = blockIdx.x * 256 + threadIdx.x;   // grid 256 -> 65536
  const uint32_t w0 = ((uint32_t)f2bf(h0[i])) << 16;   // tag 0
  const uint32_t w1 = 0xFFFFFFFFu;                     // tag 0xFFFF: never matches
  const uint32_t* p0 = hb32 + i;
  const uint32_t* p1 = hb32 + 65536 + i;
  asm volatile("global_store_dword %0, %2, off sc0 sc1\n\t"
               "global_store_dword %1, %3, off sc0 sc1"
               :: "v"(p0), "v"(p1), "v"(w0), "v"(w1) : "memory");
}

// ---------------- G = x @ U  (bf16 MFMA, 128x128x32 tiles) ----------------
__global__ void __launch_bounds__(256) gemm_xu(const unsigned short* __restrict__ A,
                                               const unsigned short* __restrict__ Bt,
                                               unsigned short* __restrict__ Gb) {
  __shared__ __align__(16) short As[4096];   // swizzled k-chunk-major 128x32
  __shared__ __align__(16) short Bs[4096];
  const int tid = threadIdx.x;
  const int l = tid & 63, w = tid >> 6;
  const int wm = w & 1, wn = w >> 1;
  const int lm = l & 15, lq = l >> 4;
  const int bid = blockIdx.x;
  const int bm = bid & 255, bn = bid >> 8;   // grid 8192 = 256 x 32

  const int i0 = tid >> 2, kc0 = tid & 3;    // staging chunk (row, kchunk)
  const int la0 = (kc0 * 128 + (i0 ^ (kc0 << 2))) * 8;
  const int la1 = la0 + 512;                 // row+64 -> swizzled index +64 -> +512 shorts
  const unsigned short* Ap = A  + (size_t)(bm * 128 + i0) * 1024 + kc0 * 8;
  const unsigned short* Bp = Bt + (size_t)(bn * 128 + i0) * 1024 + kc0 * 8;

  f32x4 acc[4][4] = {};

  for (int kt = 0; kt < 32; ++kt) {
    const int k0 = kt * 32;
    bf16x8 av0 = *(const bf16x8*)(Ap + k0);
    bf16x8 av1 = *(const bf16x8*)(Ap + 64 * 1024 + k0);
    bf16x8 bv0 = *(const bf16x8*)(Bp + k0);
    bf16x8 bv1 = *(const bf16x8*)(Bp + 64 * 1024 + k0);
    __syncthreads();
    *(bf16x8*)(As + la0) = av0;
    *(bf16x8*)(As + la1) = av1;
    *(bf16x8*)(Bs + la0) = bv0;
    *(bf16x8*)(Bs + la1) = bv1;
    __syncthreads();

    bf16x8 af[4], bfv[4];
    #pragma unroll
    for (int mt = 0; mt < 4; ++mt) {
      const int i = wm * 64 + mt * 16 + lm;
      af[mt] = *(const bf16x8*)(As + (lq * 128 + (i ^ (lq << 2))) * 8);
    }
    #pragma unroll
    for (int nt = 0; nt < 4; ++nt) {
      const int i = wn * 64 + nt * 16 + lm;
      bfv[nt] = *(const bf16x8*)(Bs + (lq * 128 + (i ^ (lq << 2))) * 8);
    }
    #pragma unroll
    for (int mt = 0; mt < 4; ++mt)
      #pragma unroll
      for (int nt = 0; nt < 4; ++nt)
        acc[mt][nt] = __builtin_amdgcn_mfma_f32_16x16x32_bf16(af[mt], bfv[nt], acc[mt][nt], 0, 0, 0);
  }

  #pragma unroll
  for (int mt = 0; mt < 4; ++mt)
    #pragma unroll
    for (int nt = 0; nt < 4; ++nt) {
      const int col = bn * 128 + wn * 64 + nt * 16 + lm;
      const int r0  = bm * 128 + wm * 64 + mt * 16 + lq * 4;
      #pragma unroll
      for (int r = 0; r < 4; ++r)
        Gb[(size_t)(r0 + r) * 4096 + col] = f2bf(acc[mt][nt][r]);
    }
}

// ---------------- persistent recurrence (tag-in-data sync) ----------------
__global__ void __launch_bounds__(256, 1) lstm_rec(
    const unsigned short* __restrict__ Gb,   // bf16 [32768][4096], row = b*512+t
    const float* __restrict__ V,             // fp32 [1024][4096]
    const float* __restrict__ Bias,          // fp32 [4096]
    const float* __restrict__ c0,            // fp32 [64][1024]
    uint32_t* __restrict__ hb32,             // u32 2x[64][1024]: bf16<<16 | tag
    float* __restrict__ out) {
  __shared__ __align__(16) float gbuf[4096];  // [w][b16][j16][g4]
  const int tid = threadIdx.x;
  const int l = tid & 63, w = tid >> 6;       // wave w owns k-quarter w
  const int lm = l & 15, lq = l >> 4;
  const int bid = blockIdx.x;
  const int mb = bid & 3;                     // batch group (independent recurrences)
  const int nh = bid >> 2;                    // hidden tile
  const int jh = nh << 4;

  // stationary V fragments: vf[ks][gate], k = w*256 + ks*32 + lq*8 + j, n = jh+lm
  bf16x8 vf[8][4];
  {
    const int col0 = jh + lm;
    #pragma unroll
    for (int ks = 0; ks < 8; ++ks) {
      const int kb = (w << 8) + (ks << 5) + (lq << 3);
      #pragma unroll
      for (int g = 0; g < 4; ++g) {
        const size_t base = (size_t)kb * 4096 + (g << 10) + col0;
        bf16x8 v;
        #pragma unroll
        for (int jj = 0; jj < 8; ++jj)
          v[jj] = (short)f2bf(V[base + (size_t)jj * 4096]);
        vf[ks][g] = v;
      }
    }
  }

  // elementwise state: one cell (b, j) per thread, c stays in a register
  const int b  = tid >> 4;
  const int j  = tid & 15;
  const int gr = (mb << 4) + b;
  float bias_r[4];
  #pragma unroll
  for (int g = 0; g < 4; ++g) bias_r[g] = Bias[(g << 10) + jh + j];
  float c = c0[(gr << 10) + jh + j];

  const int abase32 = ((mb << 4) + lm) * 1024 + (w << 8) + (lq << 3);  // u32 elems

  float gp[4], gn[4];
  {
    const size_t grow = (size_t)(gr << 9) * 4096;
    #pragma unroll
    for (int g = 0; g < 4; ++g) gp[g] = bf2f(Gb[grow + (g << 10) + jh + j]);
  }

  int budget = 20000000;  // hang-safety valve across the whole kernel

  for (int t = 0; t < 512; ++t) {
    // prefetch next step's G slice first (cached; drained by the spin's waitcnt)
    {
      const int t2 = t < 511 ? t + 1 : t;
      const size_t grow = ((size_t)(gr << 9) + t2) * 4096;
      #pragma unroll
      for (int g = 0; g < 4; ++g) gn[g] = bf2f(Gb[grow + (g << 10) + jh + j]);
    }

    // --- spin-load tagged h fragments (cache-bypass) until tags == t ---
    const uint32_t texp = (uint32_t)t;
    const uint32_t* hp = hb32 + ((t & 1) << 16) + abase32;
    u32x4 q0, q1, q2, q3, q4, q5, q6, q7, q8, q9, q10, q11, q12, q13, q14, q15;
    do {
      asm volatile(
          "global_load_dwordx4 %0, %16, off sc0 sc1\n\t"
          "global_load_dwordx4 %1, %16, off offset:16 sc0 sc1\n\t"
          "global_load_dwordx4 %2, %16, off offset:128 sc0 sc1\n\t"
          "global_load_dwordx4 %3, %16, off offset:144 sc0 sc1\n\t"
          "global_load_dwordx4 %4, %16, off offset:256 sc0 sc1\n\t"
          "global_load_dwordx4 %5, %16, off offset:272 sc0 sc1\n\t"
          "global_load_dwordx4 %6, %16, off offset:384 sc0 sc1\n\t"
          "global_load_dwordx4 %7, %16, off offset:400 sc0 sc1\n\t"
          "global_load_dwordx4 %8, %16, off offset:512 sc0 sc1\n\t"
          "global_load_dwordx4 %9, %16, off offset:528 sc0 sc1\n\t"
          "global_load_dwordx4 %10, %16, off offset:640 sc0 sc1\n\t"
          "global_load_dwordx4 %11, %16, off offset:656 sc0 sc1\n\t"
          "global_load_dwordx4 %12, %16, off offset:768 sc0 sc1\n\t"
          "global_load_dwordx4 %13, %16, off offset:784 sc0 sc1\n\t"
          "global_load_dwordx4 %14, %16, off offset:896 sc0 sc1\n\t"
          "global_load_dwordx4 %15, %16, off offset:912 sc0 sc1\n\t"
          "s_waitcnt vmcnt(0)"
          : "=&v"(q0), "=&v"(q1), "=&v"(q2), "=&v"(q3),
            "=&v"(q4), "=&v"(q5), "=&v"(q6), "=&v"(q7),
            "=&v"(q8), "=&v"(q9), "=&v"(q10), "=&v"(q11),
            "=&v"(q12), "=&v"(q13), "=&v"(q14), "=&v"(q15)
          : "v"(hp)
          : "memory");
      #define TC4(Q) ((Q[0] ^ texp) | (Q[1] ^ texp) | (Q[2] ^ texp) | (Q[3] ^ texp))
      const uint32_t dd = TC4(q0) | TC4(q1) | TC4(q2) | TC4(q3) |
                          TC4(q4) | TC4(q5) | TC4(q6) | TC4(q7) |
                          TC4(q8) | TC4(q9) | TC4(q10) | TC4(q11) |
                          TC4(q12) | TC4(q13) | TC4(q14) | TC4(q15);
      #undef TC4
      const int stale = (dd & 0xFFFFu) != 0;
      if (!__any(stale)) break;
      __builtin_amdgcn_s_sleep(2);
    } while (--budget > 0);

    // extract bf16 payloads (high 16 of each u32) into MFMA A-fragments
    bf16x8 a[8];
    #define MK(A, QA, QB) { u32x4 pa;                                     \
      pa[0] = __builtin_amdgcn_perm(QA[1], QA[0], 0x07060302u);           \
      pa[1] = __builtin_amdgcn_perm(QA[3], QA[2], 0x07060302u);           \
      pa[2] = __builtin_amdgcn_perm(QB[1], QB[0], 0x07060302u);           \
      pa[3] = __builtin_amdgcn_perm(QB[3], QB[2], 0x07060302u);           \
      A = __builtin_bit_cast(bf16x8, pa); }
    MK(a[0], q0, q1)  MK(a[1], q2, q3)  MK(a[2], q4, q5)  MK(a[3], q6, q7)
    MK(a[4], q8, q9)  MK(a[5], q10, q11) MK(a[6], q12, q13) MK(a[7], q14, q15)
    #undef MK

    f32x4 acc[4] = {};
    #pragma unroll
    for (int ks = 0; ks < 8; ++ks)
      #pragma unroll
      for (int g = 0; g < 4; ++g)
        acc[g] = __builtin_amdgcn_mfma_f32_16x16x32_bf16(a[ks], vf[ks][g], acc[g], 0, 0, 0);

    // partial (per-wave k-quarter) -> LDS for cross-wave reduction
    #pragma unroll
    for (int g = 0; g < 4; ++g)
      #pragma unroll
      for (int r = 0; r < 4; ++r)
        gbuf[((w << 8) + ((lq << 2) + r) * 16 + lm) * 4 + g] = acc[g][r];

    __syncthreads();

    f32x4 hv = *(const f32x4*)(gbuf + (tid << 2));
    hv += *(const f32x4*)(gbuf + ((256 + tid) << 2));
    hv += *(const f32x4*)(gbuf + ((512 + tid) << 2));
    hv += *(const f32x4*)(gbuf + ((768 + tid) << 2));

    const float pn = hv[0] + gp[0] + bias_r[0];
    const float pi = hv[1] + gp[1] + bias_r[1];
    const float pf = hv[2] + gp[2] + bias_r[2];
    const float po = hv[3] + gp[3] + bias_r[3];
    const float nn = tanhf_(pn);
    const float ii = sigf(pi);
    const float ff = sigf(pf);
    const float oo = sigf(po);
    c = c * ff + nn * ii;
    const float h = tanhf_(c) * oo;

    out[(size_t)gr * 524288 + ((size_t)t << 10) + jh + j] = h;

    // tagged write-through h store: payload + tag in one atomic dword
    {
      const uint32_t* sp = hb32 + (((t + 1) & 1) << 16) + (gr << 10) + jh + j;
      const uint32_t hw = (((uint32_t)f2bf(h)) << 16) | ((uint32_t)(t + 1) & 0xFFFFu);
      asm volatile("global_store_dword %0, %1, off sc0 sc1"
                   :: "v"(sp), "v"(hw) : "memory");
    }

    if (t == 511) {
      out[OUT_HF + (gr << 10) + jh + j] = h;
      out[OUT_CF + (gr << 10) + jh + j] = c;
    }
    #pragma unroll
    for (int g = 0; g < 4; ++g) gp[g] = gn[g];

    __syncthreads();   // protect gbuf reuse next iteration
  }
}

extern "C" void kernel_launch(void* const* d_in, const int* in_sizes, int n_in,
                              void* d_out, int out_size, void* d_ws, size_t ws_size,
                              hipStream_t stream) {
  const float* x  = (const float*)d_in[0];
  const float* U  = (const float*)d_in[1];
  const float* V  = (const float*)d_in[2];
  const float* Bi = (const float*)d_in[3];
  const float* h0 = (const float*)d_in[4];
  const float* c0 = (const float*)d_in[5];
  float* out = (float*)d_out;
  char* ws = (char*)d_ws;

  unsigned short* Gb = (unsigned short*)(ws + WS_G);
  unsigned short* xb = (unsigned short*)(ws + WS_XB);
  unsigned short* ut = (unsigned short*)(ws + WS_UT);
  uint32_t* hb32     = (uint32_t*)(ws + WS_HB);

  convert_x  <<<32768, 256, 0, stream>>>(x, xb);
  transpose_u<<<dim3(16, 64), 256, 0, stream>>>(U, ut);
  gemm_xu    <<<8192, 256, 0, stream>>>(xb, ut, Gb);
  // init_h AFTER gemm_xu: hb32 aliases xb's storage
  init_h     <<<256, 256, 0, stream>>>(h0, hb32);
  lstm_rec   <<<256, 256, 0, stream>>>(Gb, V, Bi, c0, hb32, out);
}